// Round 1
// baseline (1536.959 us; speedup 1.0000x reference)
//
#include <hip/hip_runtime.h>

// ---------------------------------------------------------------------------
// Petri_GCN: 3x GCNConv(64->64) + MLP readout (64->32->1) + segment-mean pool
// All fp32. Structure per layer:
//   gemm_agg:  T = act(X) @ W   (act = relu for layers 1,2 inputs)
//              A = T * invdeg + b        (self-loop term + bias fused)
//   scatter:   A[dst] += T[src] * dinv[src]*w*dinv[dst]   (atomic, wave/edge)
// ---------------------------------------------------------------------------

__global__ void deg_edges_kernel(const int* __restrict__ dst,
                                 const float* __restrict__ w,
                                 float* __restrict__ deg, int ne) {
    int e = blockIdx.x * blockDim.x + threadIdx.x;
    if (e < ne) atomicAdd(&deg[dst[e]], w[e]);
}

__global__ void deg_fin_kernel(const float* __restrict__ deg,
                               float* __restrict__ dinv,
                               float* __restrict__ invd, int n) {
    int i = blockIdx.x * blockDim.x + threadIdx.x;
    if (i < n) {
        float d = deg[i] + 1.0f;          // +1 self-loop weight
        dinv[i] = 1.0f / sqrtf(d);
        invd[i] = 1.0f / d;
    }
}

// One wave per row. Lane c holds W[:,c] in 64 VGPRs. X row read as uniform
// float4 broadcasts (cache-served, one request per wave). Writes both the
// GEMM result T and the agg-buffer init A = acc*invd + b.
// NOTE: X may alias A (in-place across layers) — safe because each row is
// read fully before its write, and rows are wave-exclusive. No __restrict__
// on X/A for that reason.
template <bool RELU>
__global__ void gemm_agg_kernel(const float* X, const float* __restrict__ W,
                                const float* __restrict__ b,
                                const float* __restrict__ invd,
                                float* __restrict__ T, float* A, int n) {
    int lane = threadIdx.x & 63;
    int wid  = (blockIdx.x * blockDim.x + threadIdx.x) >> 6;
    int nw   = (gridDim.x * blockDim.x) >> 6;
    float wc[64];
#pragma unroll
    for (int k = 0; k < 64; ++k) wc[k] = W[k * 64 + lane];
    float bl = b[lane];
    for (int r = wid; r < n; r += nw) {
        const float4* xr = (const float4*)(X + (size_t)r * 64);
        float acc = 0.0f;
#pragma unroll
        for (int k4 = 0; k4 < 16; ++k4) {
            float4 x4 = xr[k4];
            if (RELU) {
                x4.x = fmaxf(x4.x, 0.0f); x4.y = fmaxf(x4.y, 0.0f);
                x4.z = fmaxf(x4.z, 0.0f); x4.w = fmaxf(x4.w, 0.0f);
            }
            acc = fmaf(x4.x, wc[4 * k4 + 0], acc);
            acc = fmaf(x4.y, wc[4 * k4 + 1], acc);
            acc = fmaf(x4.z, wc[4 * k4 + 2], acc);
            acc = fmaf(x4.w, wc[4 * k4 + 3], acc);
        }
        T[(size_t)r * 64 + lane] = acc;
        A[(size_t)r * 64 + lane] = acc * invd[r] + bl;
    }
}

// One wave per edge, lane = channel.
__global__ void scatter_kernel(const int* __restrict__ src,
                               const int* __restrict__ dst,
                               const float* __restrict__ ew,
                               const float* __restrict__ dinv,
                               const float* __restrict__ T,
                               float* __restrict__ A, int ne) {
    int lane = threadIdx.x & 63;
    int e = (int)(((size_t)blockIdx.x * blockDim.x + threadIdx.x) >> 6);
    if (e >= ne) return;
    int s = src[e], d = dst[e];
    float norm = dinv[s] * ew[e] * dinv[d];
    float v = T[(size_t)s * 64 + lane] * norm;
    atomicAdd(&A[(size_t)d * 64 + lane], v);
}

// Thread per node: s = relu(h @ Wr0 + br0) @ Wr1 + br1; atomic segment sums.
__global__ void readout_kernel(const float* __restrict__ H,
                               const float* __restrict__ Wr0,
                               const float* __restrict__ br0,
                               const float* __restrict__ Wr1,
                               const float* __restrict__ br1,
                               const int* __restrict__ batch,
                               float* __restrict__ gsum,
                               float* __restrict__ gcnt, int n) {
    __shared__ float Ws[64 * 32];
    __shared__ float w1s[32];
    for (int i = threadIdx.x; i < 64 * 32; i += blockDim.x) Ws[i] = Wr0[i];
    if (threadIdx.x < 32) w1s[threadIdx.x] = Wr1[threadIdx.x];
    __syncthreads();
    int r = blockIdx.x * blockDim.x + threadIdx.x;
    if (r >= n) return;
    float h[64];
    const float4* hr = (const float4*)(H + (size_t)r * 64);
#pragma unroll
    for (int i = 0; i < 16; ++i) {
        float4 v = hr[i];
        h[4 * i + 0] = v.x; h[4 * i + 1] = v.y;
        h[4 * i + 2] = v.z; h[4 * i + 3] = v.w;
    }
    float ssum = 0.0f;
#pragma unroll 1
    for (int jg = 0; jg < 8; ++jg) {
        float a0 = br0[jg * 4 + 0], a1 = br0[jg * 4 + 1];
        float a2 = br0[jg * 4 + 2], a3 = br0[jg * 4 + 3];
#pragma unroll
        for (int k = 0; k < 64; ++k) {
            const float4 wv = *(const float4*)&Ws[k * 32 + jg * 4];
            a0 = fmaf(h[k], wv.x, a0);
            a1 = fmaf(h[k], wv.y, a1);
            a2 = fmaf(h[k], wv.z, a2);
            a3 = fmaf(h[k], wv.w, a3);
        }
        a0 = fmaxf(a0, 0.0f); a1 = fmaxf(a1, 0.0f);
        a2 = fmaxf(a2, 0.0f); a3 = fmaxf(a3, 0.0f);
        ssum += a0 * w1s[jg * 4 + 0] + a1 * w1s[jg * 4 + 1] +
                a2 * w1s[jg * 4 + 2] + a3 * w1s[jg * 4 + 3];
    }
    float sv = ssum + br1[0];
    int g = batch[r];
    atomicAdd(&gsum[g], sv);
    atomicAdd(&gcnt[g], 1.0f);
}

__global__ void pool_fin_kernel(const float* __restrict__ gsum,
                                const float* __restrict__ gcnt,
                                float* __restrict__ out, int ng) {
    int g = blockIdx.x * blockDim.x + threadIdx.x;
    if (g < ng) out[g] = gsum[g] / fmaxf(gcnt[g], 1.0f);
}

extern "C" void kernel_launch(void* const* d_in, const int* in_sizes, int n_in,
                              void* d_out, int out_size, void* d_ws, size_t ws_size,
                              hipStream_t stream) {
    const float* x    = (const float*)d_in[0];
    const int*   ei   = (const int*)d_in[1];
    const float* ew   = (const float*)d_in[2];
    const int*   batch= (const int*)d_in[3];
    const float* W0   = (const float*)d_in[4];
    const float* b0   = (const float*)d_in[5];
    const float* W1   = (const float*)d_in[6];
    const float* b1   = (const float*)d_in[7];
    const float* W2   = (const float*)d_in[8];
    const float* b2   = (const float*)d_in[9];
    const float* Wr0  = (const float*)d_in[10];
    const float* br0  = (const float*)d_in[11];
    const float* Wr1  = (const float*)d_in[12];
    const float* br1  = (const float*)d_in[13];
    float* out = (float*)d_out;

    int n  = in_sizes[0] / 64;   // 100000
    int ne = in_sizes[1] / 2;    // 1600000
    int ng = out_size;           // 256
    const int* srcv = ei;
    const int* dstv = ei + ne;

    char* ws = (char*)d_ws;
    size_t off = 0;
    auto alloc = [&](size_t bytes) {
        void* p = ws + off;
        off += (bytes + 255) & ~(size_t)255;
        return p;
    };
    float* T    = (float*)alloc((size_t)n * 64 * sizeof(float));
    float* A    = (float*)alloc((size_t)n * 64 * sizeof(float));
    float* deg  = (float*)alloc((size_t)n * sizeof(float));
    float* dinv = (float*)alloc((size_t)n * sizeof(float));
    float* invd = (float*)alloc((size_t)n * sizeof(float));
    float* gsum = (float*)alloc((size_t)ng * sizeof(float));
    float* gcnt = (float*)alloc((size_t)ng * sizeof(float));
    (void)ws_size;

    hipMemsetAsync(deg, 0, (size_t)n * sizeof(float), stream);
    hipMemsetAsync(gsum, 0, (size_t)ng * sizeof(float), stream);
    hipMemsetAsync(gcnt, 0, (size_t)ng * sizeof(float), stream);

    deg_edges_kernel<<<(ne + 255) / 256, 256, 0, stream>>>(dstv, ew, deg, ne);
    deg_fin_kernel<<<(n + 255) / 256, 256, 0, stream>>>(deg, dinv, invd, n);

    const int gemm_blocks = 1024;
    unsigned scat_blocks = (unsigned)(((size_t)ne * 64 + 255) / 256);

    gemm_agg_kernel<false><<<gemm_blocks, 256, 0, stream>>>(x, W0, b0, invd, T, A, n);
    scatter_kernel<<<scat_blocks, 256, 0, stream>>>(srcv, dstv, ew, dinv, T, A, ne);

    gemm_agg_kernel<true><<<gemm_blocks, 256, 0, stream>>>(A, W1, b1, invd, T, A, n);
    scatter_kernel<<<scat_blocks, 256, 0, stream>>>(srcv, dstv, ew, dinv, T, A, ne);

    gemm_agg_kernel<true><<<gemm_blocks, 256, 0, stream>>>(A, W2, b2, invd, T, A, n);
    scatter_kernel<<<scat_blocks, 256, 0, stream>>>(srcv, dstv, ew, dinv, T, A, ne);

    readout_kernel<<<(n + 255) / 256, 256, 0, stream>>>(A, Wr0, br0, Wr1, br1,
                                                        batch, gsum, gcnt, n);
    pool_fin_kernel<<<(ng + 255) / 256, 256, 0, stream>>>(gsum, gcnt, out, ng);
}

// Round 2
// 996.664 us; speedup vs baseline: 1.5421x; 1.5421x over previous
//
#include <hip/hip_runtime.h>

// ---------------------------------------------------------------------------
// Petri_GCN: 3x GCNConv(64->64) + MLP readout (64->32->1) + segment-mean pool
// All fp32 (abs threshold 1.2e-5 forbids bf16/MFMA paths; no fp32 MFMA on CDNA4).
// R1: CSR-by-dst build (counting sort) + gather replaces atomic scatter.
//     norm = dinv[s]*w*dinv[d] precomputed once into csr_w.
// ---------------------------------------------------------------------------

// Pass 1: weighted degree (float) + in-degree count (int), both by dst.
__global__ void deg_cnt_kernel(const int* __restrict__ dst,
                               const float* __restrict__ w,
                               float* __restrict__ deg,
                               int* __restrict__ cnt, int ne) {
    int e = blockIdx.x * blockDim.x + threadIdx.x;
    if (e < ne) {
        int d = dst[e];
        atomicAdd(&deg[d], w[e]);
        atomicAdd(&cnt[d], 1);
    }
}

__global__ void deg_fin_kernel(const float* __restrict__ deg,
                               float* __restrict__ dinv,
                               float* __restrict__ invd, int n) {
    int i = blockIdx.x * blockDim.x + threadIdx.x;
    if (i < n) {
        float d = deg[i] + 1.0f;          // +1 self-loop weight
        dinv[i] = 1.0f / sqrtf(d);
        invd[i] = 1.0f / d;
    }
}

// --- 3-pass exclusive scan of cnt[] -> row_ptr[] ---------------------------
#define SCAN_B 256
__global__ void scan1_kernel(const int* __restrict__ cnt,
                             int* __restrict__ excl,
                             int* __restrict__ bsum, int n) {
    __shared__ int sh[SCAN_B];
    int i = blockIdx.x * SCAN_B + threadIdx.x;
    int c = (i < n) ? cnt[i] : 0;
    sh[threadIdx.x] = c;
    __syncthreads();
    for (int off = 1; off < SCAN_B; off <<= 1) {
        int v = (threadIdx.x >= off) ? sh[threadIdx.x - off] : 0;
        __syncthreads();
        sh[threadIdx.x] += v;
        __syncthreads();
    }
    if (i < n) excl[i] = sh[threadIdx.x] - c;
    if (threadIdx.x == SCAN_B - 1) bsum[blockIdx.x] = sh[threadIdx.x];
}

// Single block: exclusive scan of block sums (nb <= 512).
__global__ void scan2_kernel(int* __restrict__ bsum, int nb) {
    __shared__ int sh[512];
    int t = threadIdx.x;
    int v = (t < nb) ? bsum[t] : 0;
    sh[t] = v;
    __syncthreads();
    for (int off = 1; off < 512; off <<= 1) {
        int u = (t >= off) ? sh[t - off] : 0;
        __syncthreads();
        sh[t] += u;
        __syncthreads();
    }
    if (t < nb) bsum[t] = sh[t] - v;
}

__global__ void scan3_kernel(const int* __restrict__ excl,
                             const int* __restrict__ bsum,
                             int* __restrict__ rptr,
                             int* __restrict__ cursor, int n) {
    int i = blockIdx.x * SCAN_B + threadIdx.x;
    if (i < n) {
        int s = excl[i] + bsum[blockIdx.x];
        rptr[i] = s;
        cursor[i] = s;
    }
}

// Fill CSR: csr_src[pos]=src, csr_w[pos]=dinv[s]*w*dinv[d].
__global__ void fill_kernel(const int* __restrict__ src,
                            const int* __restrict__ dst,
                            const float* __restrict__ ew,
                            const float* __restrict__ dinv,
                            int* __restrict__ cursor,
                            int* __restrict__ csr_src,
                            float* __restrict__ csr_w, int ne) {
    int e = blockIdx.x * blockDim.x + threadIdx.x;
    if (e >= ne) return;
    int s = src[e], d = dst[e];
    int pos = atomicAdd(&cursor[d], 1);
    csr_src[pos] = s;
    csr_w[pos] = dinv[s] * ew[e] * dinv[d];
}

// One wave per row. Lane c holds W[:,c] in 64 VGPRs. X row read as uniform
// float4 broadcasts. Writes GEMM result T and agg init A = acc*invd + b.
// X may alias A (in-place across layers): each row fully read before written,
// rows wave-exclusive.
template <bool RELU>
__global__ void gemm_agg_kernel(const float* X, const float* __restrict__ W,
                                const float* __restrict__ b,
                                const float* __restrict__ invd,
                                float* __restrict__ T, float* A, int n) {
    int lane = threadIdx.x & 63;
    int wid  = (blockIdx.x * blockDim.x + threadIdx.x) >> 6;
    int nw   = (gridDim.x * blockDim.x) >> 6;
    float wc[64];
#pragma unroll
    for (int k = 0; k < 64; ++k) wc[k] = W[k * 64 + lane];
    float bl = b[lane];
    for (int r = wid; r < n; r += nw) {
        const float4* xr = (const float4*)(X + (size_t)r * 64);
        float acc = 0.0f;
#pragma unroll
        for (int k4 = 0; k4 < 16; ++k4) {
            float4 x4 = xr[k4];
            if (RELU) {
                x4.x = fmaxf(x4.x, 0.0f); x4.y = fmaxf(x4.y, 0.0f);
                x4.z = fmaxf(x4.z, 0.0f); x4.w = fmaxf(x4.w, 0.0f);
            }
            acc = fmaf(x4.x, wc[4 * k4 + 0], acc);
            acc = fmaf(x4.y, wc[4 * k4 + 1], acc);
            acc = fmaf(x4.z, wc[4 * k4 + 2], acc);
            acc = fmaf(x4.w, wc[4 * k4 + 3], acc);
        }
        T[(size_t)r * 64 + lane] = acc;
        A[(size_t)r * 64 + lane] = acc * invd[r] + bl;
    }
}

// One wave per dst row; lane = channel. A[r] += sum_j T[src_j] * w_j.
__global__ void gather_kernel(const int* __restrict__ csr_src,
                              const float* __restrict__ csr_w,
                              const int* __restrict__ rptr,
                              const int* __restrict__ cnt,
                              const float* __restrict__ T,
                              float* __restrict__ A, int n) {
    int lane = threadIdx.x & 63;
    int r = (int)(((size_t)blockIdx.x * blockDim.x + threadIdx.x) >> 6);
    if (r >= n) return;
    int start = rptr[r];
    int m = cnt[r];
    float acc0 = 0.0f, acc1 = 0.0f;
    int j = 0;
    for (; j + 1 < m; j += 2) {
        int   s0 = csr_src[start + j],     s1 = csr_src[start + j + 1];
        float w0 = csr_w[start + j],       w1 = csr_w[start + j + 1];
        acc0 = fmaf(T[(size_t)s0 * 64 + lane], w0, acc0);
        acc1 = fmaf(T[(size_t)s1 * 64 + lane], w1, acc1);
    }
    if (j < m)
        acc0 = fmaf(T[(size_t)csr_src[start + j] * 64 + lane],
                    csr_w[start + j], acc0);
    size_t o = (size_t)r * 64 + lane;
    A[o] += acc0 + acc1;
}

// Thread per node: s = relu(h @ Wr0 + br0) @ Wr1 + br1; atomic segment sums.
__global__ void readout_kernel(const float* __restrict__ H,
                               const float* __restrict__ Wr0,
                               const float* __restrict__ br0,
                               const float* __restrict__ Wr1,
                               const float* __restrict__ br1,
                               const int* __restrict__ batch,
                               float* __restrict__ gsum,
                               float* __restrict__ gcnt, int n) {
    __shared__ float Ws[64 * 32];
    __shared__ float w1s[32];
    for (int i = threadIdx.x; i < 64 * 32; i += blockDim.x) Ws[i] = Wr0[i];
    if (threadIdx.x < 32) w1s[threadIdx.x] = Wr1[threadIdx.x];
    __syncthreads();
    int r = blockIdx.x * blockDim.x + threadIdx.x;
    if (r >= n) return;
    float h[64];
    const float4* hr = (const float4*)(H + (size_t)r * 64);
#pragma unroll
    for (int i = 0; i < 16; ++i) {
        float4 v = hr[i];
        h[4 * i + 0] = v.x; h[4 * i + 1] = v.y;
        h[4 * i + 2] = v.z; h[4 * i + 3] = v.w;
    }
    float ssum = 0.0f;
#pragma unroll 1
    for (int jg = 0; jg < 8; ++jg) {
        float a0 = br0[jg * 4 + 0], a1 = br0[jg * 4 + 1];
        float a2 = br0[jg * 4 + 2], a3 = br0[jg * 4 + 3];
#pragma unroll
        for (int k = 0; k < 64; ++k) {
            const float4 wv = *(const float4*)&Ws[k * 32 + jg * 4];
            a0 = fmaf(h[k], wv.x, a0);
            a1 = fmaf(h[k], wv.y, a1);
            a2 = fmaf(h[k], wv.z, a2);
            a3 = fmaf(h[k], wv.w, a3);
        }
        a0 = fmaxf(a0, 0.0f); a1 = fmaxf(a1, 0.0f);
        a2 = fmaxf(a2, 0.0f); a3 = fmaxf(a3, 0.0f);
        ssum += a0 * w1s[jg * 4 + 0] + a1 * w1s[jg * 4 + 1] +
                a2 * w1s[jg * 4 + 2] + a3 * w1s[jg * 4 + 3];
    }
    float sv = ssum + br1[0];
    int g = batch[r];
    atomicAdd(&gsum[g], sv);
    atomicAdd(&gcnt[g], 1.0f);
}

__global__ void pool_fin_kernel(const float* __restrict__ gsum,
                                const float* __restrict__ gcnt,
                                float* __restrict__ out, int ng) {
    int g = blockIdx.x * blockDim.x + threadIdx.x;
    if (g < ng) out[g] = gsum[g] / fmaxf(gcnt[g], 1.0f);
}

extern "C" void kernel_launch(void* const* d_in, const int* in_sizes, int n_in,
                              void* d_out, int out_size, void* d_ws, size_t ws_size,
                              hipStream_t stream) {
    const float* x    = (const float*)d_in[0];
    const int*   ei   = (const int*)d_in[1];
    const float* ew   = (const float*)d_in[2];
    const int*   batch= (const int*)d_in[3];
    const float* W0   = (const float*)d_in[4];
    const float* b0   = (const float*)d_in[5];
    const float* W1   = (const float*)d_in[6];
    const float* b1   = (const float*)d_in[7];
    const float* W2   = (const float*)d_in[8];
    const float* b2   = (const float*)d_in[9];
    const float* Wr0  = (const float*)d_in[10];
    const float* br0  = (const float*)d_in[11];
    const float* Wr1  = (const float*)d_in[12];
    const float* br1  = (const float*)d_in[13];
    float* out = (float*)d_out;

    int n  = in_sizes[0] / 64;   // 100000
    int ne = in_sizes[1] / 2;    // 1600000
    int ng = out_size;           // 256
    const int* srcv = ei;
    const int* dstv = ei + ne;

    char* ws = (char*)d_ws;
    size_t off = 0;
    auto alloc = [&](size_t bytes) {
        void* p = ws + off;
        off += (bytes + 255) & ~(size_t)255;
        return p;
    };
    float* T      = (float*)alloc((size_t)n * 64 * sizeof(float));
    float* A      = (float*)alloc((size_t)n * 64 * sizeof(float));
    float* deg    = (float*)alloc((size_t)n * sizeof(float));
    float* dinv   = (float*)alloc((size_t)n * sizeof(float));
    float* invd   = (float*)alloc((size_t)n * sizeof(float));
    int*   cnt    = (int*)alloc((size_t)n * sizeof(int));
    int*   excl   = (int*)alloc((size_t)n * sizeof(int));
    int*   rptr   = (int*)alloc((size_t)n * sizeof(int));
    int*   cursor = (int*)alloc((size_t)n * sizeof(int));
    int*   bsum   = (int*)alloc(512 * sizeof(int));
    int*   csr_src= (int*)alloc((size_t)ne * sizeof(int));
    float* csr_w  = (float*)alloc((size_t)ne * sizeof(float));
    float* gsum   = (float*)alloc((size_t)ng * sizeof(float));
    float* gcnt   = (float*)alloc((size_t)ng * sizeof(float));
    (void)ws_size;

    int nb = (n + SCAN_B - 1) / SCAN_B;   // 391 <= 512

    hipMemsetAsync(deg, 0, (size_t)n * sizeof(float), stream);
    hipMemsetAsync(cnt, 0, (size_t)n * sizeof(int), stream);
    hipMemsetAsync(gsum, 0, (size_t)ng * sizeof(float), stream);
    hipMemsetAsync(gcnt, 0, (size_t)ng * sizeof(float), stream);

    deg_cnt_kernel<<<(ne + 255) / 256, 256, 0, stream>>>(dstv, ew, deg, cnt, ne);
    deg_fin_kernel<<<(n + 255) / 256, 256, 0, stream>>>(deg, dinv, invd, n);
    scan1_kernel<<<nb, SCAN_B, 0, stream>>>(cnt, excl, bsum, n);
    scan2_kernel<<<1, 512, 0, stream>>>(bsum, nb);
    scan3_kernel<<<nb, SCAN_B, 0, stream>>>(excl, bsum, rptr, cursor, n);
    fill_kernel<<<(ne + 255) / 256, 256, 0, stream>>>(srcv, dstv, ew, dinv,
                                                      cursor, csr_src, csr_w, ne);

    const int gemm_blocks = 1024;
    unsigned gat_blocks = (unsigned)(((size_t)n * 64 + 255) / 256);

    gemm_agg_kernel<false><<<gemm_blocks, 256, 0, stream>>>(x, W0, b0, invd, T, A, n);
    gather_kernel<<<gat_blocks, 256, 0, stream>>>(csr_src, csr_w, rptr, cnt, T, A, n);

    gemm_agg_kernel<true><<<gemm_blocks, 256, 0, stream>>>(A, W1, b1, invd, T, A, n);
    gather_kernel<<<gat_blocks, 256, 0, stream>>>(csr_src, csr_w, rptr, cnt, T, A, n);

    gemm_agg_kernel<true><<<gemm_blocks, 256, 0, stream>>>(A, W2, b2, invd, T, A, n);
    gather_kernel<<<gat_blocks, 256, 0, stream>>>(csr_src, csr_w, rptr, cnt, T, A, n);

    readout_kernel<<<(n + 255) / 256, 256, 0, stream>>>(A, Wr0, br0, Wr1, br1,
                                                        batch, gsum, gcnt, n);
    pool_fin_kernel<<<(ng + 255) / 256, 256, 0, stream>>>(gsum, gcnt, out, ng);
}

// Round 3
// 665.099 us; speedup vs baseline: 2.3109x; 1.4985x over previous
//
#include <hip/hip_runtime.h>

// ---------------------------------------------------------------------------
// Petri_GCN: 3x GCNConv(64->64) + MLP readout (64->32->1) + segment-mean pool
// All fp32 (abs threshold forbids bf16/MFMA; no fp32 MFMA on CDNA4).
// R1: CSR-by-dst (counting sort) + gather instead of atomic scatter.
// R2: readout wave-segmented atomics (batch sorted -> 1-2 heads/wave);
//     gather uses 4x(16-lane x float4) layout: 1 VMEM instr per 4 edges.
// ---------------------------------------------------------------------------

__global__ void deg_cnt_kernel(const int* __restrict__ dst,
                               const float* __restrict__ w,
                               float* __restrict__ deg,
                               int* __restrict__ cnt, int ne) {
    int e = blockIdx.x * blockDim.x + threadIdx.x;
    if (e < ne) {
        int d = dst[e];
        atomicAdd(&deg[d], w[e]);
        atomicAdd(&cnt[d], 1);
    }
}

__global__ void deg_fin_kernel(const float* __restrict__ deg,
                               float* __restrict__ dinv,
                               float* __restrict__ invd, int n) {
    int i = blockIdx.x * blockDim.x + threadIdx.x;
    if (i < n) {
        float d = deg[i] + 1.0f;          // +1 self-loop weight
        dinv[i] = 1.0f / sqrtf(d);
        invd[i] = 1.0f / d;
    }
}

// --- 3-pass exclusive scan of cnt[] -> row_ptr[] ---------------------------
#define SCAN_B 256
__global__ void scan1_kernel(const int* __restrict__ cnt,
                             int* __restrict__ excl,
                             int* __restrict__ bsum, int n) {
    __shared__ int sh[SCAN_B];
    int i = blockIdx.x * SCAN_B + threadIdx.x;
    int c = (i < n) ? cnt[i] : 0;
    sh[threadIdx.x] = c;
    __syncthreads();
    for (int off = 1; off < SCAN_B; off <<= 1) {
        int v = (threadIdx.x >= off) ? sh[threadIdx.x - off] : 0;
        __syncthreads();
        sh[threadIdx.x] += v;
        __syncthreads();
    }
    if (i < n) excl[i] = sh[threadIdx.x] - c;
    if (threadIdx.x == SCAN_B - 1) bsum[blockIdx.x] = sh[threadIdx.x];
}

__global__ void scan2_kernel(int* __restrict__ bsum, int nb) {
    __shared__ int sh[512];
    int t = threadIdx.x;
    int v = (t < nb) ? bsum[t] : 0;
    sh[t] = v;
    __syncthreads();
    for (int off = 1; off < 512; off <<= 1) {
        int u = (t >= off) ? sh[t - off] : 0;
        __syncthreads();
        sh[t] += u;
        __syncthreads();
    }
    if (t < nb) bsum[t] = sh[t] - v;
}

__global__ void scan3_kernel(const int* __restrict__ excl,
                             const int* __restrict__ bsum,
                             int* __restrict__ rptr,
                             int* __restrict__ cursor, int n) {
    int i = blockIdx.x * SCAN_B + threadIdx.x;
    if (i < n) {
        int s = excl[i] + bsum[blockIdx.x];
        rptr[i] = s;
        cursor[i] = s;
    }
}

__global__ void fill_kernel(const int* __restrict__ src,
                            const int* __restrict__ dst,
                            const float* __restrict__ ew,
                            const float* __restrict__ dinv,
                            int* __restrict__ cursor,
                            int* __restrict__ csr_src,
                            float* __restrict__ csr_w, int ne) {
    int e = blockIdx.x * blockDim.x + threadIdx.x;
    if (e >= ne) return;
    int s = src[e], d = dst[e];
    int pos = atomicAdd(&cursor[d], 1);
    csr_src[pos] = s;
    csr_w[pos] = dinv[s] * ew[e] * dinv[d];
}

// One wave per row. Lane c holds W[:,c] in 64 VGPRs. X row read as uniform
// float4 broadcasts. Writes GEMM result T and agg init A = acc*invd + b.
// X may alias A (in-place across layers): each row fully read before written,
// rows wave-exclusive.
template <bool RELU>
__global__ void gemm_agg_kernel(const float* X, const float* __restrict__ W,
                                const float* __restrict__ b,
                                const float* __restrict__ invd,
                                float* __restrict__ T, float* A, int n) {
    int lane = threadIdx.x & 63;
    int wid  = (blockIdx.x * blockDim.x + threadIdx.x) >> 6;
    int nw   = (gridDim.x * blockDim.x) >> 6;
    float wc[64];
#pragma unroll
    for (int k = 0; k < 64; ++k) wc[k] = W[k * 64 + lane];
    float bl = b[lane];
    for (int r = wid; r < n; r += nw) {
        const float4* xr = (const float4*)(X + (size_t)r * 64);
        float acc = 0.0f;
#pragma unroll
        for (int k4 = 0; k4 < 16; ++k4) {
            float4 x4 = xr[k4];
            if (RELU) {
                x4.x = fmaxf(x4.x, 0.0f); x4.y = fmaxf(x4.y, 0.0f);
                x4.z = fmaxf(x4.z, 0.0f); x4.w = fmaxf(x4.w, 0.0f);
            }
            acc = fmaf(x4.x, wc[4 * k4 + 0], acc);
            acc = fmaf(x4.y, wc[4 * k4 + 1], acc);
            acc = fmaf(x4.z, wc[4 * k4 + 2], acc);
            acc = fmaf(x4.w, wc[4 * k4 + 3], acc);
        }
        T[(size_t)r * 64 + lane] = acc;
        A[(size_t)r * 64 + lane] = acc * invd[r] + bl;
    }
}

// One wave per dst row. 4 subgroups of 16 lanes; subgroup handles every 4th
// edge, lane's float4 covers channels 4*cl..4*cl+3. One dwordx4 VMEM instr
// serves 4 edges (1 KB). Subgroup partials combined via 2 shfl_xor steps.
__global__ void gather_kernel(const int* __restrict__ csr_src,
                              const float* __restrict__ csr_w,
                              const int* __restrict__ rptr,
                              const int* __restrict__ cnt,
                              const float* __restrict__ T,
                              float* __restrict__ A, int n) {
    int lane = threadIdx.x & 63;
    int r = (int)(((size_t)blockIdx.x * blockDim.x + threadIdx.x) >> 6);
    if (r >= n) return;
    int sub = lane >> 4;          // 0..3: edge subgroup
    int cl  = lane & 15;          // channel quad
    int start = rptr[r];
    int m = cnt[r];
    float4 a0 = {0.f, 0.f, 0.f, 0.f};
    float4 a1 = {0.f, 0.f, 0.f, 0.f};
    int j = sub;
    for (; j + 4 < m; j += 8) {
        int   s0 = csr_src[start + j];
        float w0 = csr_w[start + j];
        int   s1 = csr_src[start + j + 4];
        float w1 = csr_w[start + j + 4];
        float4 t0 = *(const float4*)&T[(size_t)s0 * 64 + cl * 4];
        float4 t1 = *(const float4*)&T[(size_t)s1 * 64 + cl * 4];
        a0.x = fmaf(t0.x, w0, a0.x); a0.y = fmaf(t0.y, w0, a0.y);
        a0.z = fmaf(t0.z, w0, a0.z); a0.w = fmaf(t0.w, w0, a0.w);
        a1.x = fmaf(t1.x, w1, a1.x); a1.y = fmaf(t1.y, w1, a1.y);
        a1.z = fmaf(t1.z, w1, a1.z); a1.w = fmaf(t1.w, w1, a1.w);
    }
    if (j < m) {
        int   s0 = csr_src[start + j];
        float w0 = csr_w[start + j];
        float4 t0 = *(const float4*)&T[(size_t)s0 * 64 + cl * 4];
        a0.x = fmaf(t0.x, w0, a0.x); a0.y = fmaf(t0.y, w0, a0.y);
        a0.z = fmaf(t0.z, w0, a0.z); a0.w = fmaf(t0.w, w0, a0.w);
    }
    a0.x += a1.x; a0.y += a1.y; a0.z += a1.z; a0.w += a1.w;
#pragma unroll
    for (int off = 16; off < 64; off <<= 1) {
        a0.x += __shfl_xor(a0.x, off);
        a0.y += __shfl_xor(a0.y, off);
        a0.z += __shfl_xor(a0.z, off);
        a0.w += __shfl_xor(a0.w, off);
    }
    if (sub == 0) {
        float4* ap = (float4*)&A[(size_t)r * 64 + cl * 4];
        float4 cur = *ap;
        cur.x += a0.x; cur.y += a0.y; cur.z += a0.z; cur.w += a0.w;
        *ap = cur;
    }
}

// Thread per node: sv = relu(h @ Wr0 + br0) @ Wr1 + br1.
// batch is sorted -> wave-segmented suffix reduction, heads do the atomics.
__global__ void readout_kernel(const float* __restrict__ H,
                               const float* __restrict__ Wr0,
                               const float* __restrict__ br0,
                               const float* __restrict__ Wr1,
                               const float* __restrict__ br1,
                               const int* __restrict__ batch,
                               float* __restrict__ gsum,
                               float* __restrict__ gcnt, int n) {
    __shared__ float Ws[64 * 32];
    __shared__ float w1s[32];
    for (int i = threadIdx.x; i < 64 * 32; i += blockDim.x) Ws[i] = Wr0[i];
    if (threadIdx.x < 32) w1s[threadIdx.x] = Wr1[threadIdx.x];
    __syncthreads();
    int r = blockIdx.x * blockDim.x + threadIdx.x;
    int lane = threadIdx.x & 63;
    float sv = 0.0f;
    int g = -1;
    if (r < n) {
        float h[64];
        const float4* hr = (const float4*)(H + (size_t)r * 64);
#pragma unroll
        for (int i = 0; i < 16; ++i) {
            float4 v = hr[i];
            h[4 * i + 0] = v.x; h[4 * i + 1] = v.y;
            h[4 * i + 2] = v.z; h[4 * i + 3] = v.w;
        }
        float ssum = 0.0f;
#pragma unroll 1
        for (int jg = 0; jg < 8; ++jg) {
            float a0 = br0[jg * 4 + 0], a1 = br0[jg * 4 + 1];
            float a2 = br0[jg * 4 + 2], a3 = br0[jg * 4 + 3];
#pragma unroll
            for (int k = 0; k < 64; ++k) {
                const float4 wv = *(const float4*)&Ws[k * 32 + jg * 4];
                a0 = fmaf(h[k], wv.x, a0);
                a1 = fmaf(h[k], wv.y, a1);
                a2 = fmaf(h[k], wv.z, a2);
                a3 = fmaf(h[k], wv.w, a3);
            }
            a0 = fmaxf(a0, 0.0f); a1 = fmaxf(a1, 0.0f);
            a2 = fmaxf(a2, 0.0f); a3 = fmaxf(a3, 0.0f);
            ssum += a0 * w1s[jg * 4 + 0] + a1 * w1s[jg * 4 + 1] +
                    a2 * w1s[jg * 4 + 2] + a3 * w1s[jg * 4 + 3];
        }
        sv = ssum + br1[0];
        g = batch[r];
    }
    // wave-segmented suffix sum over contiguous equal-g runs
    float c = (r < n) ? 1.0f : 0.0f;
#pragma unroll
    for (int off = 1; off < 64; off <<= 1) {
        int   og = __shfl_down(g, off);
        float ov = __shfl_down(sv, off);
        float oc = __shfl_down(c, off);
        if ((lane + off) < 64 && og == g) { sv += ov; c += oc; }
    }
    int gprev = __shfl_up(g, 1);
    bool head = (lane == 0) || (gprev != g);
    if (head && g >= 0) {
        atomicAdd(&gsum[g], sv);
        atomicAdd(&gcnt[g], c);
    }
}

__global__ void pool_fin_kernel(const float* __restrict__ gsum,
                                const float* __restrict__ gcnt,
                                float* __restrict__ out, int ng) {
    int g = blockIdx.x * blockDim.x + threadIdx.x;
    if (g < ng) out[g] = gsum[g] / fmaxf(gcnt[g], 1.0f);
}

extern "C" void kernel_launch(void* const* d_in, const int* in_sizes, int n_in,
                              void* d_out, int out_size, void* d_ws, size_t ws_size,
                              hipStream_t stream) {
    const float* x    = (const float*)d_in[0];
    const int*   ei   = (const int*)d_in[1];
    const float* ew   = (const float*)d_in[2];
    const int*   batch= (const int*)d_in[3];
    const float* W0   = (const float*)d_in[4];
    const float* b0   = (const float*)d_in[5];
    const float* W1   = (const float*)d_in[6];
    const float* b1   = (const float*)d_in[7];
    const float* W2   = (const float*)d_in[8];
    const float* b2   = (const float*)d_in[9];
    const float* Wr0  = (const float*)d_in[10];
    const float* br0  = (const float*)d_in[11];
    const float* Wr1  = (const float*)d_in[12];
    const float* br1  = (const float*)d_in[13];
    float* out = (float*)d_out;

    int n  = in_sizes[0] / 64;   // 100000
    int ne = in_sizes[1] / 2;    // 1600000
    int ng = out_size;           // 256
    const int* srcv = ei;
    const int* dstv = ei + ne;

    char* ws = (char*)d_ws;
    size_t off = 0;
    auto alloc = [&](size_t bytes) {
        void* p = ws + off;
        off += (bytes + 255) & ~(size_t)255;
        return p;
    };
    float* T      = (float*)alloc((size_t)n * 64 * sizeof(float));
    float* A      = (float*)alloc((size_t)n * 64 * sizeof(float));
    float* deg    = (float*)alloc((size_t)n * sizeof(float));
    float* dinv   = (float*)alloc((size_t)n * sizeof(float));
    float* invd   = (float*)alloc((size_t)n * sizeof(float));
    int*   cnt    = (int*)alloc((size_t)n * sizeof(int));
    int*   excl   = (int*)alloc((size_t)n * sizeof(int));
    int*   rptr   = (int*)alloc((size_t)n * sizeof(int));
    int*   cursor = (int*)alloc((size_t)n * sizeof(int));
    int*   bsum   = (int*)alloc(512 * sizeof(int));
    int*   csr_src= (int*)alloc((size_t)ne * sizeof(int));
    float* csr_w  = (float*)alloc((size_t)ne * sizeof(float));
    float* gsum   = (float*)alloc((size_t)ng * sizeof(float));
    float* gcnt   = (float*)alloc((size_t)ng * sizeof(float));
    (void)ws_size;

    int nb = (n + SCAN_B - 1) / SCAN_B;   // 391 <= 512

    hipMemsetAsync(deg, 0, (size_t)n * sizeof(float), stream);
    hipMemsetAsync(cnt, 0, (size_t)n * sizeof(int), stream);
    hipMemsetAsync(gsum, 0, (size_t)ng * sizeof(float), stream);
    hipMemsetAsync(gcnt, 0, (size_t)ng * sizeof(float), stream);

    deg_cnt_kernel<<<(ne + 255) / 256, 256, 0, stream>>>(dstv, ew, deg, cnt, ne);
    deg_fin_kernel<<<(n + 255) / 256, 256, 0, stream>>>(deg, dinv, invd, n);
    scan1_kernel<<<nb, SCAN_B, 0, stream>>>(cnt, excl, bsum, n);
    scan2_kernel<<<1, 512, 0, stream>>>(bsum, nb);
    scan3_kernel<<<nb, SCAN_B, 0, stream>>>(excl, bsum, rptr, cursor, n);
    fill_kernel<<<(ne + 255) / 256, 256, 0, stream>>>(srcv, dstv, ew, dinv,
                                                      cursor, csr_src, csr_w, ne);

    const int gemm_blocks = 1024;
    unsigned gat_blocks = (unsigned)(((size_t)n * 64 + 255) / 256);

    gemm_agg_kernel<false><<<gemm_blocks, 256, 0, stream>>>(x, W0, b0, invd, T, A, n);
    gather_kernel<<<gat_blocks, 256, 0, stream>>>(csr_src, csr_w, rptr, cnt, T, A, n);

    gemm_agg_kernel<true><<<gemm_blocks, 256, 0, stream>>>(A, W1, b1, invd, T, A, n);
    gather_kernel<<<gat_blocks, 256, 0, stream>>>(csr_src, csr_w, rptr, cnt, T, A, n);

    gemm_agg_kernel<true><<<gemm_blocks, 256, 0, stream>>>(A, W2, b2, invd, T, A, n);
    gather_kernel<<<gat_blocks, 256, 0, stream>>>(csr_src, csr_w, rptr, cnt, T, A, n);

    readout_kernel<<<(n + 255) / 256, 256, 0, stream>>>(A, Wr0, br0, Wr1, br1,
                                                        batch, gsum, gcnt, n);
    pool_fin_kernel<<<(ng + 255) / 256, 256, 0, stream>>>(gsum, gcnt, out, ng);
}